// Round 1
// baseline (298.924 us; speedup 1.0000x reference)
//
#include <hip/hip_runtime.h>
#include <hip/hip_bf16.h>
#include <math.h>

// Problem constants
#define T_LEN   4096
#define D_DIM   512
#define H_NUM   8
#define HD_DIM  64
#define W_WIN   32
#define HID_DIM 1536
#define M_ROWS  8192   // B*T
#define QKV_LD  1536   // fused q|kv row stride
#define BK 64

typedef __hip_bfloat16 bf16;
typedef __bf16  bf16x8 __attribute__((ext_vector_type(8)));
typedef float   f32x4  __attribute__((ext_vector_type(4)));

#define G_AS __attribute__((address_space(1)))
#define L_AS __attribute__((address_space(3)))

__device__ __forceinline__ float b2f(bf16 x) { return __bfloat162float(x); }
__device__ __forceinline__ bf16  f2b(float x){ return __float2bfloat16(x); }

// 16B async global->LDS DMA (gfx950). Dest must be linear: base + lane*16.
__device__ __forceinline__ void gload_lds16(const bf16* g, bf16* l) {
  __builtin_amdgcn_global_load_lds((const G_AS unsigned int*)g,
                                   (L_AS unsigned int*)l, 16, 0, 0);
}

__device__ __forceinline__ float rdP(const void* p, int i, bool f32) {
  return f32 ? ((const float*)p)[i] : b2f(((const bf16*)p)[i]);
}

__device__ __forceinline__ float wave_reduce_sum(float v) {
  #pragma unroll
  for (int off = 32; off; off >>= 1) v += __shfl_xor(v, off, 64);
  return v;
}

// Wave-parallel dtype detection over a fixed 256 dwords of x (deterministic).
__device__ __forceinline__ bool detect_f32(const unsigned* __restrict__ x) {
  int lane = threadIdx.x & 63;
  int votes = 0;
  #pragma unroll
  for (int i = 0; i < 4; ++i) {
    unsigned e = (x[lane * 4 + i] >> 7) & 0xffu;
    votes += (e >= 90u && e <= 140u) ? 1 : 0;
  }
  float v = wave_reduce_sum((float)votes);
  return v < 200.f;
}

// XCD-aware 1-D block swizzle (R8-validated): lid%8 = XCD; same-by tiles
// land on one XCD so the A row-panel is fetched into exactly one L2.
// All grids used are multiples of 8 -> bijective.
__device__ __forceinline__ void swizzle_xy(int gx, int& bx, int& by) {
  int lid = blockIdx.x;
  int sub = lid & 7;
  int grp = lid >> 3;
  bx = grp % gx;
  by = (grp / gx) * 8 + sub;
}

// ---------------------------------------------------------------------------
// LayerNorm (R2-validated numerics; self-detecting dtype).
// ---------------------------------------------------------------------------
__global__ __launch_bounds__(256) void ln_kernel(
    const void* __restrict__ in, const void* __restrict__ g, const void* __restrict__ bb,
    void* __restrict__ out, int mode,
    const void* __restrict__ freqs, const void* __restrict__ phases,
    const void* __restrict__ amp,
    const unsigned* __restrict__ xdet, int in_follows, int out_follows)
{
  bool f32  = detect_f32(xdet);
  bool inF  = f32 && (in_follows != 0);
  bool outF = f32 && (out_follows != 0);

  int wave = threadIdx.x >> 6;
  int lane = threadIdx.x & 63;
  int row  = blockIdx.x * 4 + wave;

  float x[8];
  if (inF) {
    const float* rp = (const float*)in + (size_t)row * D_DIM + lane * 8;
    float4 v0 = *reinterpret_cast<const float4*>(rp);
    float4 v1 = *reinterpret_cast<const float4*>(rp + 4);
    x[0]=v0.x; x[1]=v0.y; x[2]=v0.z; x[3]=v0.w;
    x[4]=v1.x; x[5]=v1.y; x[6]=v1.z; x[7]=v1.w;
  } else {
    bf16x8 v = *reinterpret_cast<const bf16x8*>(
        (const bf16*)in + (size_t)row * D_DIM + lane * 8);
    #pragma unroll
    for (int i = 0; i < 8; ++i) x[i] = (float)v[i];
  }

  float s = 0.f, s2 = 0.f;
  #pragma unroll
  for (int i = 0; i < 8; ++i) { s += x[i]; s2 += x[i]*x[i]; }
  s  = wave_reduce_sum(s);
  s2 = wave_reduce_sum(s2);
  float mu   = s * (1.f / D_DIM);
  float var  = s2 * (1.f / D_DIM) - mu * mu;
  float rstd = rsqrtf(var + 1e-5f);

  int t = row & (T_LEN - 1);
  float ampf = (mode == 1) ? rdP(amp, 0, f32) : 0.f;

  float o[8];
  #pragma unroll
  for (int i = 0; i < 8; ++i) {
    int d = lane * 8 + i;
    float val = (x[i] - mu) * rstd * rdP(g, d, f32) + rdP(bb, d, f32);
    if (mode == 1) {
      float m = sinf(fmaf((float)t, rdP(freqs, d, f32), rdP(phases, d, f32)));
      val *= (1.f + ampf * m);
    }
    o[i] = val;
  }

  if (outF) {
    float* op = (float*)out + (size_t)row * D_DIM + lane * 8;
    *reinterpret_cast<float4*>(op)     = make_float4(o[0], o[1], o[2], o[3]);
    *reinterpret_cast<float4*>(op + 4) = make_float4(o[4], o[5], o[6], o[7]);
  } else {
    bf16x8 ov;
    #pragma unroll
    for (int i = 0; i < 8; ++i) ov[i] = (__bf16)o[i];
    *reinterpret_cast<bf16x8*>((bf16*)out + (size_t)row * D_DIM + lane * 8) = ov;
  }
}

// ---------------------------------------------------------------------------
// Fused weight transposes (R6-validated; self-detecting dtype).
// ---------------------------------------------------------------------------
__global__ __launch_bounds__(256) void transpose_all_kernel(
    const void* s0, const void* s1, const void* s2, const void* s3,
    const void* s4, const void* s5,
    bf16* d0, bf16* d1, bf16* d2, bf16* d3, bf16* d4, bf16* d5,
    const unsigned* __restrict__ xdet)
{
  bool f32 = detect_f32(xdet);
  int bid = blockIdx.x;
  const void* src; bf16* dst; int R, C, lid, tiles_x;
  if      (bid < 256)  { src=s0; dst=d0; R=512;  C=512;  lid=bid;      tiles_x=16; }
  else if (bid < 768)  { src=s1; dst=d1; R=512;  C=1024; lid=bid-256;  tiles_x=32; }
  else if (bid < 1024) { src=s2; dst=d2; R=512;  C=512;  lid=bid-768;  tiles_x=16; }
  else if (bid < 1792) { src=s3; dst=d3; R=512;  C=1536; lid=bid-1024; tiles_x=48; }
  else if (bid < 2560) { src=s4; dst=d4; R=512;  C=1536; lid=bid-1792; tiles_x=48; }
  else                 { src=s5; dst=d5; R=1536; C=512;  lid=bid-2560; tiles_x=16; }

  __shared__ bf16 tile[32][33];
  int tx = threadIdx.x & 31;
  int ty = threadIdx.x >> 5;
  int c0 = (lid % tiles_x) * 32;
  int r0 = (lid / tiles_x) * 32;
  #pragma unroll
  for (int j = 0; j < 32; j += 8)
    tile[ty + j][tx] = f2b(rdP(src, (size_t)(r0 + ty + j) * C + c0 + tx, f32));
  __syncthreads();
  #pragma unroll
  for (int j = 0; j < 32; j += 8)
    dst[(size_t)(c0 + ty + j) * R + r0 + tx] = tile[tx][ty + j];
}

// ---------------------------------------------------------------------------
// 128 x BNT tile GEMM, BK=64, m97-class structure:
//   - staging via global_load_lds width=16 (async DMA, no VGPR round-trip)
//   - LDS kept LINEAR (DMA writes base+lane*16); XOR swizzle applied on the
//     SOURCE address (inverse) and on the ds_read (forward) — rule #21
//   - 4 waves, each owns a 64 x (BNT/2) output tile: 4 x (BNT/32) frags
//   - per K-step/wave: 32 (BNT=128) or 16 (BNT=64) MFMA vs 16/12 ds_read_b128
// mode 0: C = A@Bt^T. mode 1: C = A@Bt^T + extra.
// BNT=128 for big-N GEMMs (grid mult of 8, >=3 blocks/CU);
// BNT=64  for N=512 GEMMs (512 blocks -> 2 blocks/CU instead of 1).
// ---------------------------------------------------------------------------
template<int BNT>
__global__ __launch_bounds__(256) void gemm_tile_kernel(
    const bf16* __restrict__ A, const bf16* __restrict__ Bt,
    bf16* Cout, const bf16* extra, int N, int K, int lda, int mode, int gx)
{
  constexpr int BJ = BNT / 32;                 // B staging issues / frags per ko
  __shared__ alignas(16) bf16 As[128 * BK];    // 16 KB
  __shared__ alignas(16) bf16 Bs[BNT * BK];    // 16 or 8 KB

  int bx, by; swizzle_xy(gx, bx, by);
  int mbase = by * 128, nbase = bx * BNT;
  int tid  = threadIdx.x;
  int lane = tid & 63;
  int wid  = tid >> 6;
  int quad = lane >> 4, l16 = lane & 15;
  int wm = (wid >> 1) * 64, wn = (wid & 1) * (BNT / 2);

  // Staging map: issue j covers LDS rows j*32 + tid/8, col8 = tid%8.
  // LDS[row][c8] holds global[row][c8 ^ (row&7)]  (both-sides swizzle).
  int srow = tid >> 3;
  int scol = (tid & 7) ^ (srow & 7);
  const bf16* Ag = A  + (size_t)(mbase + srow) * lda + scol * 8;
  const bf16* Bg = Bt + (size_t)(nbase + srow) * K   + scol * 8;

  f32x4 acc[4][BJ] = {};

  for (int kleft = K / BK; kleft > 0; --kleft) {
    __syncthreads();                 // prev iteration's fragment reads done
    #pragma unroll
    for (int j = 0; j < 4; ++j)
      gload_lds16(Ag + (size_t)(j * 32) * lda, &As[j * 2048 + tid * 8]);
    #pragma unroll
    for (int j = 0; j < BJ; ++j)
      gload_lds16(Bg + (size_t)(j * 32) * K,   &Bs[j * 2048 + tid * 8]);
    Ag += BK; Bg += BK;
    __syncthreads();                 // vmcnt(0) drain: DMA visible

    #pragma unroll
    for (int ko = 0; ko < 2; ++ko) {
      bf16x8 a[4], b[BJ];
      int c = ((ko * 4 + quad) ^ (l16 & 7)) * 8;
      #pragma unroll
      for (int i = 0; i < 4; ++i)
        a[i] = *reinterpret_cast<const bf16x8*>(&As[(wm + i * 16 + l16) * BK + c]);
      #pragma unroll
      for (int j = 0; j < BJ; ++j)
        b[j] = *reinterpret_cast<const bf16x8*>(&Bs[(wn + j * 16 + l16) * BK + c]);
      #pragma unroll
      for (int i = 0; i < 4; ++i)
        #pragma unroll
        for (int j = 0; j < BJ; ++j)
          acc[i][j] = __builtin_amdgcn_mfma_f32_16x16x32_bf16(a[i], b[j], acc[i][j], 0, 0, 0);
    }
  }

  #pragma unroll
  for (int i = 0; i < 4; ++i)
    #pragma unroll
    for (int j = 0; j < BJ; ++j)
      #pragma unroll
      for (int r = 0; r < 4; ++r) {
        int row = mbase + wm + i * 16 + quad * 4 + r;
        int col = nbase + wn + j * 16 + l16;
        size_t idx = (size_t)row * N + col;
        float cv = acc[i][j][r];
        if (mode == 1) cv += b2f(extra[idx]);
        Cout[idx] = f2b(cv);
      }
}

// ---------------------------------------------------------------------------
// Fused gate+val GEMM, 128x64 tile, same m97-class DMA structure:
// act = silu(A@Wg) * (A@Wv). 32 KB LDS, 32 MFMA per K-step per wave.
// ---------------------------------------------------------------------------
__global__ __launch_bounds__(256) void gateval_kernel(
    const bf16* __restrict__ A, const bf16* __restrict__ Btg,
    const bf16* __restrict__ Btv, bf16* __restrict__ Cout,
    int N, int K, int lda, int gx)
{
  __shared__ alignas(16) bf16 As [128 * BK];   // 16 KB
  __shared__ alignas(16) bf16 Bgs[ 64 * BK];   //  8 KB
  __shared__ alignas(16) bf16 Bvs[ 64 * BK];   //  8 KB

  int bx, by; swizzle_xy(gx, bx, by);
  int mbase = by * 128, nbase = bx * 64;
  int tid  = threadIdx.x;
  int lane = tid & 63;
  int wid  = tid >> 6;
  int quad = lane >> 4, l16 = lane & 15;
  int wm = (wid >> 1) * 64, wn = (wid & 1) * 32;

  int srow = tid >> 3;
  int scol = (tid & 7) ^ (srow & 7);
  const bf16* Ag = A   + (size_t)(mbase + srow) * lda + scol * 8;
  const bf16* Gg = Btg + (size_t)(nbase + srow) * K   + scol * 8;
  const bf16* Vg = Btv + (size_t)(nbase + srow) * K   + scol * 8;

  f32x4 accg[4][2] = {};
  f32x4 accv[4][2] = {};

  for (int kleft = K / BK; kleft > 0; --kleft) {
    __syncthreads();
    #pragma unroll
    for (int j = 0; j < 4; ++j)
      gload_lds16(Ag + (size_t)(j * 32) * lda, &As[j * 2048 + tid * 8]);
    #pragma unroll
    for (int j = 0; j < 2; ++j) {
      gload_lds16(Gg + (size_t)(j * 32) * K, &Bgs[j * 2048 + tid * 8]);
      gload_lds16(Vg + (size_t)(j * 32) * K, &Bvs[j * 2048 + tid * 8]);
    }
    Ag += BK; Gg += BK; Vg += BK;
    __syncthreads();

    #pragma unroll
    for (int ko = 0; ko < 2; ++ko) {
      bf16x8 a[4], bg[2], bv[2];
      int c = ((ko * 4 + quad) ^ (l16 & 7)) * 8;
      #pragma unroll
      for (int i = 0; i < 4; ++i)
        a[i]  = *reinterpret_cast<const bf16x8*>(&As [(wm + i * 16 + l16) * BK + c]);
      #pragma unroll
      for (int j = 0; j < 2; ++j) {
        bg[j] = *reinterpret_cast<const bf16x8*>(&Bgs[(wn + j * 16 + l16) * BK + c]);
        bv[j] = *reinterpret_cast<const bf16x8*>(&Bvs[(wn + j * 16 + l16) * BK + c]);
      }
      #pragma unroll
      for (int i = 0; i < 4; ++i)
        #pragma unroll
        for (int j = 0; j < 2; ++j) {
          accg[i][j] = __builtin_amdgcn_mfma_f32_16x16x32_bf16(a[i], bg[j], accg[i][j], 0, 0, 0);
          accv[i][j] = __builtin_amdgcn_mfma_f32_16x16x32_bf16(a[i], bv[j], accv[i][j], 0, 0, 0);
        }
    }
  }

  #pragma unroll
  for (int i = 0; i < 4; ++i)
    #pragma unroll
    for (int j = 0; j < 2; ++j)
      #pragma unroll
      for (int r = 0; r < 4; ++r) {
        int row = mbase + wm + i * 16 + quad * 4 + r;
        int col = nbase + wn + j * 16 + l16;
        float g = accg[i][j][r];
        float v = accv[i][j][r];
        Cout[(size_t)row * N + col] = f2b(g / (1.f + expf(-g)) * v);
      }
}

// ---------------------------------------------------------------------------
// MFMA sliding-window sigmoid attention (R4-R8-validated layouts).
// ---------------------------------------------------------------------------
#define VT_BYTES 9216
#define PL_BYTES 2304
#define ATTN_SET (VT_BYTES + PL_BYTES)
__device__ __forceinline__ int vt_addr(int d, int t) { return d * 144 + t * 2; }

__global__ __launch_bounds__(256) void attn_mfma_kernel(bf16* qkv)
{
  __shared__ alignas(16) char lds_raw[4 * ATTN_SET];
  int lane = threadIdx.x & 63;
  int widx = threadIdx.x >> 6;
  int u    = blockIdx.x * 4 + widx;
  int tile = u >> 3, head = u & 7;
  int rowbase = tile * 16;
  int t0   = rowbase & (T_LEN - 1);
  int l16  = lane & 15, quad = lane >> 4;

  char* wbase = lds_raw + widx * ATTN_SET;
  char* Vl = wbase;
  bf16* Pl = (bf16*)(wbase + VT_BYTES);

  #pragma unroll
  for (int it = 0; it < 6; ++it) {
    int chunk = it * 64 + lane;
    int t  = chunk >> 3;
    int dc = chunk & 7;
    int row = rowbase - 32 + t;
    if (row < 0) row = 0;             // garbage ok: masked by tau=0
    bf16x8 v = *reinterpret_cast<const bf16x8*>(
        qkv + (size_t)row * QKV_LD + 512 + head * 128 + 64 + dc * 8);
    #pragma unroll
    for (int jj = 0; jj < 8; ++jj)
      *(bf16*)(Vl + vt_addr(dc * 8 + jj, t)) = (bf16)(__bf16)v[jj];
  }
  bf16x8 z = {};
  *reinterpret_cast<bf16x8*>(Vl + vt_addr(lane, 48)) = z;
  *reinterpret_cast<bf16x8*>(Vl + vt_addr(lane, 56)) = z;

  bf16x8 aq0, aq1;
  {
    const bf16* qrow = qkv + (size_t)(rowbase + l16) * QKV_LD + head * HD_DIM + quad * 8;
    aq0 = *reinterpret_cast<const bf16x8*>(qrow);
    aq1 = *reinterpret_cast<const bf16x8*>(qrow + 32);
  }

  f32x4 sacc[3] = {};
  #pragma unroll
  for (int jt = 0; jt < 3; ++jt) {
    int tok = rowbase - 32 + jt * 16 + l16;
    if (tok < 0) tok = 0;             // garbage ok: masked
    const bf16* krow = qkv + (size_t)tok * QKV_LD + 512 + head * 128 + quad * 8;
    bf16x8 b0 = *reinterpret_cast<const bf16x8*>(krow);
    bf16x8 b1 = *reinterpret_cast<const bf16x8*>(krow + 32);
    sacc[jt] = __builtin_amdgcn_mfma_f32_16x16x32_bf16(aq0, b0, sacc[jt], 0, 0, 0);
    sacc[jt] = __builtin_amdgcn_mfma_f32_16x16x32_bf16(aq1, b1, sacc[jt], 0, 0, 0);
  }

  #pragma unroll
  for (int jt = 0; jt < 3; ++jt) {
    int j = jt * 16 + l16;
    #pragma unroll
    for (int r = 0; r < 4; ++r) {
      int i = quad * 4 + r;
      bool valid = (j >= i) && (j <= i + 31) && (t0 - 32 + j >= 0);
      float tau = valid ? 1.f / (1.f + expf(-sacc[jt][r] * 0.125f)) : 0.f;
      Pl[i * 72 + j] = f2b(tau);
    }
  }
  #pragma unroll
  for (int r = 0; r < 4; ++r) Pl[(quad * 4 + r) * 72 + 48 + l16] = f2b(0.f);

  __syncthreads();   // uniform; orders LDS writes->reads across the block

  bf16x8 ap0 = *reinterpret_cast<const bf16x8*>((char*)Pl + l16 * 144 + quad * 16);
  bf16x8 ap1 = *reinterpret_cast<const bf16x8*>((char*)Pl + l16 * 144 + 64 + quad * 16);

  f32x4 macc[4] = {};
  #pragma unroll
  for (int nt = 0; nt < 4; ++nt) {
    int d = nt * 16 + l16;
    bf16x8 bv0 = *reinterpret_cast<const bf16x8*>(Vl + vt_addr(d, quad * 8));
    bf16x8 bv1 = *reinterpret_cast<const bf16x8*>(Vl + vt_addr(d, 32 + quad * 8));
    macc[nt] = __builtin_amdgcn_mfma_f32_16x16x32_bf16(ap0, bv0, macc[nt], 0, 0, 0);
    macc[nt] = __builtin_amdgcn_mfma_f32_16x16x32_bf16(ap1, bv1, macc[nt], 0, 0, 0);
  }

  #pragma unroll
  for (int nt = 0; nt < 4; ++nt)
    #pragma unroll
    for (int r = 0; r < 4; ++r)
      qkv[(size_t)(rowbase + quad * 4 + r) * QKV_LD + head * HD_DIM + nt * 16 + l16] =
          f2b(macc[nt][r]);
}

// ---------------------------------------------------------------------------
extern "C" void kernel_launch(void* const* d_in, const int* in_sizes, int n_in,
                              void* d_out, int out_size, void* d_ws, size_t ws_size,
                              hipStream_t stream)
{
  const void* x      = d_in[0];
  const void* pre_g  = d_in[1];
  const void* pre_b  = d_in[2];
  const void* wq     = d_in[3];
  const void* wkv    = d_in[4];
  const void* wo     = d_in[5];
  const void* attn_g = d_in[6];
  const void* attn_b = d_in[7];
  const void* freqs  = d_in[8];
  const void* phases = d_in[9];
  const void* amp    = d_in[10];
  const void* w_gate = d_in[11];
  const void* w_val  = d_in[12];
  const void* w_proj = d_in[13];
  const void* ffn_g  = d_in[14];
  const void* ffn_b  = d_in[15];
  const unsigned* xdet = (const unsigned*)x;

  char* ws = (char*)d_ws;
  bf16* Btqkv = (bf16*)(ws + 512);       // 1536 x 512
  bf16* Bto   = (bf16*)(ws + 1573376);   //  512 x 512
  bf16* Btg   = (bf16*)(ws + 2097664);   // 1536 x 512
  bf16* Btv   = (bf16*)(ws + 3670528);   // 1536 x 512
  bf16* Btp   = (bf16*)(ws + 5243392);   //  512 x 1536
  bf16* h     = (bf16*)(ws + 6816256);   // 8192 x 512   (h -> s1 -> y -> u)
  bf16* qkvb  = (bf16*)(ws + 15204864);  // 8192 x 1536  (q|kv; msg in-place; then act)
  bf16* gb    = qkvb;

  transpose_all_kernel<<<3328, 256, 0, stream>>>(
      wq, wkv, wo, w_gate, w_val, w_proj,
      Btqkv, Btqkv + 512 * 512, Bto, Btg, Btv, Btp, xdet);

  // h = LN(x)
  ln_kernel<<<2048, 256, 0, stream>>>(x, pre_g, pre_b, h, 0,
                                      nullptr, nullptr, nullptr, xdet, 1, 0);

  // qkv = h @ [wq|wkv]  (fused, N=1536): 128x128 tiles, 768 blocks (~3/CU)
  gemm_tile_kernel<128><<<768, 256, 0, stream>>>(h, Btqkv, qkvb, nullptr,
                                                 1536, 512, 512, 0, 12);

  // msg = window-attention (in-place over q slot)
  attn_mfma_kernel<<<1024, 256, 0, stream>>>(qkvb);

  // s1 = h + msg @ wo  (N=512): 128x64 tiles, 512 blocks (2/CU)
  gemm_tile_kernel<64><<<512, 256, 0, stream>>>(qkvb, Bto, h, h,
                                                512, 512, QKV_LD, 1, 8);

  // y = LN(s1) * (1 + amp*sin(t*freqs+phases))
  ln_kernel<<<2048, 256, 0, stream>>>(h, attn_g, attn_b, h, 1,
                                      freqs, phases, amp, xdet, 0, 0);

  // act = silu(y @ w_gate) * (y @ w_val): 128x64 tiles, 1536 blocks
  gateval_kernel<<<1536, 256, 0, stream>>>(h, Btg, Btv, gb,
                                           1536, 512, 512, 24);

  // u = y + act @ w_proj  (N=512, K=1536): 128x64 tiles, 512 blocks
  gemm_tile_kernel<64><<<512, 256, 0, stream>>>(gb, Btp, h, h,
                                                512, 1536, QKV_LD, 1, 8);

  // out = LN(u)
  ln_kernel<<<2048, 256, 0, stream>>>(h, ffn_g, ffn_b, d_out, 0,
                                      nullptr, nullptr, nullptr, xdet, 0, 1);
}

// Round 2
// 297.695 us; speedup vs baseline: 1.0041x; 1.0041x over previous
//
#include <hip/hip_runtime.h>
#include <hip/hip_bf16.h>
#include <math.h>

// Problem constants
#define T_LEN   4096
#define D_DIM   512
#define H_NUM   8
#define HD_DIM  64
#define W_WIN   32
#define HID_DIM 1536
#define M_ROWS  8192   // B*T
#define QKV_LD  1536   // fused q|kv row stride
#define BK 64

typedef __hip_bfloat16 bf16;
typedef __bf16  bf16x8 __attribute__((ext_vector_type(8)));
typedef float   f32x4  __attribute__((ext_vector_type(4)));

#define G_AS __attribute__((address_space(1)))
#define L_AS __attribute__((address_space(3)))

#define SBAR()        __builtin_amdgcn_s_barrier()
#define SCHED_FENCE() __builtin_amdgcn_sched_barrier(0)
#define WAIT_VM(N)    asm volatile("s_waitcnt vmcnt(" #N ")" ::: "memory")
#define WAIT_LGKM0()  asm volatile("s_waitcnt lgkmcnt(0)" ::: "memory")

__device__ __forceinline__ float b2f(bf16 x) { return __bfloat162float(x); }
__device__ __forceinline__ bf16  f2b(float x){ return __float2bfloat16(x); }

// 16B async global->LDS DMA (gfx950). Dest must be linear: base + lane*16.
__device__ __forceinline__ void gload_lds16(const bf16* g, bf16* l) {
  __builtin_amdgcn_global_load_lds((const G_AS unsigned int*)g,
                                   (L_AS unsigned int*)l, 16, 0, 0);
}

__device__ __forceinline__ float rdP(const void* p, int i, bool f32) {
  return f32 ? ((const float*)p)[i] : b2f(((const bf16*)p)[i]);
}

__device__ __forceinline__ float wave_reduce_sum(float v) {
  #pragma unroll
  for (int off = 32; off; off >>= 1) v += __shfl_xor(v, off, 64);
  return v;
}

// Wave-parallel dtype detection over a fixed 256 dwords of x (deterministic).
__device__ __forceinline__ bool detect_f32(const unsigned* __restrict__ x) {
  int lane = threadIdx.x & 63;
  int votes = 0;
  #pragma unroll
  for (int i = 0; i < 4; ++i) {
    unsigned e = (x[lane * 4 + i] >> 7) & 0xffu;
    votes += (e >= 90u && e <= 140u) ? 1 : 0;
  }
  float v = wave_reduce_sum((float)votes);
  return v < 200.f;
}

// XCD-aware 1-D block swizzle (R8-validated): lid%8 = XCD; same-by tiles
// land on one XCD so the A row-panel is fetched into exactly one L2.
// All grids used are multiples of 8 -> bijective.
__device__ __forceinline__ void swizzle_xy(int gx, int& bx, int& by) {
  int lid = blockIdx.x;
  int sub = lid & 7;
  int grp = lid >> 3;
  bx = grp % gx;
  by = (grp / gx) * 8 + sub;
}

// ---------------------------------------------------------------------------
// LayerNorm (R2-validated numerics; self-detecting dtype).
// ---------------------------------------------------------------------------
__global__ __launch_bounds__(256) void ln_kernel(
    const void* __restrict__ in, const void* __restrict__ g, const void* __restrict__ bb,
    void* __restrict__ out, int mode,
    const void* __restrict__ freqs, const void* __restrict__ phases,
    const void* __restrict__ amp,
    const unsigned* __restrict__ xdet, int in_follows, int out_follows)
{
  bool f32  = detect_f32(xdet);
  bool inF  = f32 && (in_follows != 0);
  bool outF = f32 && (out_follows != 0);

  int wave = threadIdx.x >> 6;
  int lane = threadIdx.x & 63;
  int row  = blockIdx.x * 4 + wave;

  float x[8];
  if (inF) {
    const float* rp = (const float*)in + (size_t)row * D_DIM + lane * 8;
    float4 v0 = *reinterpret_cast<const float4*>(rp);
    float4 v1 = *reinterpret_cast<const float4*>(rp + 4);
    x[0]=v0.x; x[1]=v0.y; x[2]=v0.z; x[3]=v0.w;
    x[4]=v1.x; x[5]=v1.y; x[6]=v1.z; x[7]=v1.w;
  } else {
    bf16x8 v = *reinterpret_cast<const bf16x8*>(
        (const bf16*)in + (size_t)row * D_DIM + lane * 8);
    #pragma unroll
    for (int i = 0; i < 8; ++i) x[i] = (float)v[i];
  }

  float s = 0.f, s2 = 0.f;
  #pragma unroll
  for (int i = 0; i < 8; ++i) { s += x[i]; s2 += x[i]*x[i]; }
  s  = wave_reduce_sum(s);
  s2 = wave_reduce_sum(s2);
  float mu   = s * (1.f / D_DIM);
  float var  = s2 * (1.f / D_DIM) - mu * mu;
  float rstd = rsqrtf(var + 1e-5f);

  int t = row & (T_LEN - 1);
  float ampf = (mode == 1) ? rdP(amp, 0, f32) : 0.f;

  float o[8];
  #pragma unroll
  for (int i = 0; i < 8; ++i) {
    int d = lane * 8 + i;
    float val = (x[i] - mu) * rstd * rdP(g, d, f32) + rdP(bb, d, f32);
    if (mode == 1) {
      float m = sinf(fmaf((float)t, rdP(freqs, d, f32), rdP(phases, d, f32)));
      val *= (1.f + ampf * m);
    }
    o[i] = val;
  }

  if (outF) {
    float* op = (float*)out + (size_t)row * D_DIM + lane * 8;
    *reinterpret_cast<float4*>(op)     = make_float4(o[0], o[1], o[2], o[3]);
    *reinterpret_cast<float4*>(op + 4) = make_float4(o[4], o[5], o[6], o[7]);
  } else {
    bf16x8 ov;
    #pragma unroll
    for (int i = 0; i < 8; ++i) ov[i] = (__bf16)o[i];
    *reinterpret_cast<bf16x8*>((bf16*)out + (size_t)row * D_DIM + lane * 8) = ov;
  }
}

// ---------------------------------------------------------------------------
// Fused weight transposes (R6-validated; self-detecting dtype).
// ---------------------------------------------------------------------------
__global__ __launch_bounds__(256) void transpose_all_kernel(
    const void* s0, const void* s1, const void* s2, const void* s3,
    const void* s4, const void* s5,
    bf16* d0, bf16* d1, bf16* d2, bf16* d3, bf16* d4, bf16* d5,
    const unsigned* __restrict__ xdet)
{
  bool f32 = detect_f32(xdet);
  int bid = blockIdx.x;
  const void* src; bf16* dst; int R, C, lid, tiles_x;
  if      (bid < 256)  { src=s0; dst=d0; R=512;  C=512;  lid=bid;      tiles_x=16; }
  else if (bid < 768)  { src=s1; dst=d1; R=512;  C=1024; lid=bid-256;  tiles_x=32; }
  else if (bid < 1024) { src=s2; dst=d2; R=512;  C=512;  lid=bid-768;  tiles_x=16; }
  else if (bid < 1792) { src=s3; dst=d3; R=512;  C=1536; lid=bid-1024; tiles_x=48; }
  else if (bid < 2560) { src=s4; dst=d4; R=512;  C=1536; lid=bid-1792; tiles_x=48; }
  else                 { src=s5; dst=d5; R=1536; C=512;  lid=bid-2560; tiles_x=16; }

  __shared__ bf16 tile[32][33];
  int tx = threadIdx.x & 31;
  int ty = threadIdx.x >> 5;
  int c0 = (lid % tiles_x) * 32;
  int r0 = (lid / tiles_x) * 32;
  #pragma unroll
  for (int j = 0; j < 32; j += 8)
    tile[ty + j][tx] = f2b(rdP(src, (size_t)(r0 + ty + j) * C + c0 + tx, f32));
  __syncthreads();
  #pragma unroll
  for (int j = 0; j < 32; j += 8)
    dst[(size_t)(c0 + ty + j) * R + r0 + tx] = tile[tx][ty + j];
}

// ---------------------------------------------------------------------------
// 128 x BNT tile GEMM, BK=64 — double-buffered LDS + counted vmcnt pipeline
// (T3/T4 "minimum 2-phase"):
//   STAGE(t+1 -> buf^1)            (global_load_lds width=16, stays in flight)
//   s_waitcnt vmcnt(L)             (waits ONLY tile t, issued one iter ago)
//   s_barrier                      (tile-t data visible to all waves)
//   ds_read buf[cur] + MFMA        (overlaps tile t+1's DMA)
//   s_waitcnt lgkmcnt(0); s_barrier (buf[cur] safe to overwrite at t+2)
// LDS kept LINEAR for the DMA; XOR swizzle applied on the SOURCE address
// (inverse) and on the ds_read (forward) — rule #21, R7/R8-validated.
// L = gload_lds per tile per wave: 8 (BNT=128) or 6 (BNT=64).
// mode 0: C = A@Bt^T. mode 1: C = A@Bt^T + extra.
// ---------------------------------------------------------------------------
template<int BNT>
__global__ __launch_bounds__(256) void gemm_tile_kernel(
    const bf16* __restrict__ A, const bf16* __restrict__ Bt,
    bf16* Cout, const bf16* extra, int N, int K, int lda, int mode, int gx)
{
  constexpr int BJ = BNT / 32;                 // B staging issues / frags per ko
  __shared__ alignas(16) bf16 As[2][128 * BK]; // 2 x 16 KB
  __shared__ alignas(16) bf16 Bs[2][BNT * BK]; // 2 x 16/8 KB

  int bx, by; swizzle_xy(gx, bx, by);
  int mbase = by * 128, nbase = bx * BNT;
  int tid  = threadIdx.x;
  int lane = tid & 63;
  int wid  = tid >> 6;
  int quad = lane >> 4, l16 = lane & 15;
  int wm = (wid >> 1) * 64, wn = (wid & 1) * (BNT / 2);

  // Staging map: issue j covers LDS rows j*32 + tid/8, col8 = tid%8.
  // LDS[row][c8] holds global[row][c8 ^ (row&7)]  (both-sides swizzle).
  int srow = tid >> 3;
  int scol = (tid & 7) ^ (srow & 7);
  const bf16* Ag = A  + (size_t)(mbase + srow) * lda + scol * 8;
  const bf16* Bg = Bt + (size_t)(nbase + srow) * K   + scol * 8;

  f32x4 acc[4][BJ] = {};
  int nk = K / BK;

  // prologue: stage tile 0 into buf 0
  #pragma unroll
  for (int j = 0; j < 4; ++j)
    gload_lds16(Ag + (size_t)(j * 32) * lda, &As[0][j * 2048 + tid * 8]);
  #pragma unroll
  for (int j = 0; j < BJ; ++j)
    gload_lds16(Bg + (size_t)(j * 32) * K,   &Bs[0][j * 2048 + tid * 8]);
  Ag += BK; Bg += BK;

  for (int t = 0; t < nk; ++t) {
    int cur = t & 1;
    if (t + 1 < nk) {
      int nxt = cur ^ 1;
      #pragma unroll
      for (int j = 0; j < 4; ++j)
        gload_lds16(Ag + (size_t)(j * 32) * lda, &As[nxt][j * 2048 + tid * 8]);
      #pragma unroll
      for (int j = 0; j < BJ; ++j)
        gload_lds16(Bg + (size_t)(j * 32) * K,   &Bs[nxt][j * 2048 + tid * 8]);
      Ag += BK; Bg += BK;
      if constexpr (BNT == 128) { WAIT_VM(8); } else { WAIT_VM(6); }
    } else {
      WAIT_VM(0);
    }
    SBAR();            // tile t visible to all waves; t+1 still in flight
    SCHED_FENCE();

    #pragma unroll
    for (int ko = 0; ko < 2; ++ko) {
      bf16x8 a[4], b[BJ];
      int c = ((ko * 4 + quad) ^ (l16 & 7)) * 8;
      #pragma unroll
      for (int i = 0; i < 4; ++i)
        a[i] = *reinterpret_cast<const bf16x8*>(&As[cur][(wm + i * 16 + l16) * BK + c]);
      #pragma unroll
      for (int j = 0; j < BJ; ++j)
        b[j] = *reinterpret_cast<const bf16x8*>(&Bs[cur][(wn + j * 16 + l16) * BK + c]);
      #pragma unroll
      for (int i = 0; i < 4; ++i)
        #pragma unroll
        for (int j = 0; j < BJ; ++j)
          acc[i][j] = __builtin_amdgcn_mfma_f32_16x16x32_bf16(a[i], b[j], acc[i][j], 0, 0, 0);
    }

    WAIT_LGKM0();      // this wave's ds_reads of buf[cur] complete
    SBAR();            // all waves done with buf[cur]: safe to overwrite at t+2
    SCHED_FENCE();
  }

  #pragma unroll
  for (int i = 0; i < 4; ++i)
    #pragma unroll
    for (int j = 0; j < BJ; ++j)
      #pragma unroll
      for (int r = 0; r < 4; ++r) {
        int row = mbase + wm + i * 16 + quad * 4 + r;
        int col = nbase + wn + j * 16 + l16;
        size_t idx = (size_t)row * N + col;
        float cv = acc[i][j][r];
        if (mode == 1) cv += b2f(extra[idx]);
        Cout[idx] = f2b(cv);
      }
}

// ---------------------------------------------------------------------------
// Fused gate+val GEMM, 128x64 tile, same double-buffered counted-vmcnt
// pipeline: act = silu(A@Wg) * (A@Wv). 64 KB LDS, L=8 stage issues/tile.
// ---------------------------------------------------------------------------
__global__ __launch_bounds__(256) void gateval_kernel(
    const bf16* __restrict__ A, const bf16* __restrict__ Btg,
    const bf16* __restrict__ Btv, bf16* __restrict__ Cout,
    int N, int K, int lda, int gx)
{
  __shared__ alignas(16) bf16 As [2][128 * BK];  // 2 x 16 KB
  __shared__ alignas(16) bf16 Bgs[2][ 64 * BK];  // 2 x  8 KB
  __shared__ alignas(16) bf16 Bvs[2][ 64 * BK];  // 2 x  8 KB

  int bx, by; swizzle_xy(gx, bx, by);
  int mbase = by * 128, nbase = bx * 64;
  int tid  = threadIdx.x;
  int lane = tid & 63;
  int wid  = tid >> 6;
  int quad = lane >> 4, l16 = lane & 15;
  int wm = (wid >> 1) * 64, wn = (wid & 1) * 32;

  int srow = tid >> 3;
  int scol = (tid & 7) ^ (srow & 7);
  const bf16* Ag = A   + (size_t)(mbase + srow) * lda + scol * 8;
  const bf16* Gg = Btg + (size_t)(nbase + srow) * K   + scol * 8;
  const bf16* Vg = Btv + (size_t)(nbase + srow) * K   + scol * 8;

  f32x4 accg[4][2] = {};
  f32x4 accv[4][2] = {};
  int nk = K / BK;

  #pragma unroll
  for (int j = 0; j < 4; ++j)
    gload_lds16(Ag + (size_t)(j * 32) * lda, &As[0][j * 2048 + tid * 8]);
  #pragma unroll
  for (int j = 0; j < 2; ++j) {
    gload_lds16(Gg + (size_t)(j * 32) * K, &Bgs[0][j * 2048 + tid * 8]);
    gload_lds16(Vg + (size_t)(j * 32) * K, &Bvs[0][j * 2048 + tid * 8]);
  }
  Ag += BK; Gg += BK; Vg += BK;

  for (int t = 0; t < nk; ++t) {
    int cur = t & 1;
    if (t + 1 < nk) {
      int nxt = cur ^ 1;
      #pragma unroll
      for (int j = 0; j < 4; ++j)
        gload_lds16(Ag + (size_t)(j * 32) * lda, &As[nxt][j * 2048 + tid * 8]);
      #pragma unroll
      for (int j = 0; j < 2; ++j) {
        gload_lds16(Gg + (size_t)(j * 32) * K, &Bgs[nxt][j * 2048 + tid * 8]);
        gload_lds16(Vg + (size_t)(j * 32) * K, &Bvs[nxt][j * 2048 + tid * 8]);
      }
      Ag += BK; Gg += BK; Vg += BK;
      WAIT_VM(8);
    } else {
      WAIT_VM(0);
    }
    SBAR();
    SCHED_FENCE();

    #pragma unroll
    for (int ko = 0; ko < 2; ++ko) {
      bf16x8 a[4], bg[2], bv[2];
      int c = ((ko * 4 + quad) ^ (l16 & 7)) * 8;
      #pragma unroll
      for (int i = 0; i < 4; ++i)
        a[i]  = *reinterpret_cast<const bf16x8*>(&As [cur][(wm + i * 16 + l16) * BK + c]);
      #pragma unroll
      for (int j = 0; j < 2; ++j) {
        bg[j] = *reinterpret_cast<const bf16x8*>(&Bgs[cur][(wn + j * 16 + l16) * BK + c]);
        bv[j] = *reinterpret_cast<const bf16x8*>(&Bvs[cur][(wn + j * 16 + l16) * BK + c]);
      }
      #pragma unroll
      for (int i = 0; i < 4; ++i)
        #pragma unroll
        for (int j = 0; j < 2; ++j) {
          accg[i][j] = __builtin_amdgcn_mfma_f32_16x16x32_bf16(a[i], bg[j], accg[i][j], 0, 0, 0);
          accv[i][j] = __builtin_amdgcn_mfma_f32_16x16x32_bf16(a[i], bv[j], accv[i][j], 0, 0, 0);
        }
    }

    WAIT_LGKM0();
    SBAR();
    SCHED_FENCE();
  }

  #pragma unroll
  for (int i = 0; i < 4; ++i)
    #pragma unroll
    for (int j = 0; j < 2; ++j)
      #pragma unroll
      for (int r = 0; r < 4; ++r) {
        int row = mbase + wm + i * 16 + quad * 4 + r;
        int col = nbase + wn + j * 16 + l16;
        float g = accg[i][j][r];
        float v = accv[i][j][r];
        Cout[(size_t)row * N + col] = f2b(g / (1.f + expf(-g)) * v);
      }
}

// ---------------------------------------------------------------------------
// MFMA sliding-window sigmoid attention (R4-R8-validated layouts).
// ---------------------------------------------------------------------------
#define VT_BYTES 9216
#define PL_BYTES 2304
#define ATTN_SET (VT_BYTES + PL_BYTES)
__device__ __forceinline__ int vt_addr(int d, int t) { return d * 144 + t * 2; }

__global__ __launch_bounds__(256) void attn_mfma_kernel(bf16* qkv)
{
  __shared__ alignas(16) char lds_raw[4 * ATTN_SET];
  int lane = threadIdx.x & 63;
  int widx = threadIdx.x >> 6;
  int u    = blockIdx.x * 4 + widx;
  int tile = u >> 3, head = u & 7;
  int rowbase = tile * 16;
  int t0   = rowbase & (T_LEN - 1);
  int l16  = lane & 15, quad = lane >> 4;

  char* wbase = lds_raw + widx * ATTN_SET;
  char* Vl = wbase;
  bf16* Pl = (bf16*)(wbase + VT_BYTES);

  #pragma unroll
  for (int it = 0; it < 6; ++it) {
    int chunk = it * 64 + lane;
    int t  = chunk >> 3;
    int dc = chunk & 7;
    int row = rowbase - 32 + t;
    if (row < 0) row = 0;             // garbage ok: masked by tau=0
    bf16x8 v = *reinterpret_cast<const bf16x8*>(
        qkv + (size_t)row * QKV_LD + 512 + head * 128 + 64 + dc * 8);
    #pragma unroll
    for (int jj = 0; jj < 8; ++jj)
      *(bf16*)(Vl + vt_addr(dc * 8 + jj, t)) = (bf16)(__bf16)v[jj];
  }
  bf16x8 z = {};
  *reinterpret_cast<bf16x8*>(Vl + vt_addr(lane, 48)) = z;
  *reinterpret_cast<bf16x8*>(Vl + vt_addr(lane, 56)) = z;

  bf16x8 aq0, aq1;
  {
    const bf16* qrow = qkv + (size_t)(rowbase + l16) * QKV_LD + head * HD_DIM + quad * 8;
    aq0 = *reinterpret_cast<const bf16x8*>(qrow);
    aq1 = *reinterpret_cast<const bf16x8*>(qrow + 32);
  }

  f32x4 sacc[3] = {};
  #pragma unroll
  for (int jt = 0; jt < 3; ++jt) {
    int tok = rowbase - 32 + jt * 16 + l16;
    if (tok < 0) tok = 0;             // garbage ok: masked
    const bf16* krow = qkv + (size_t)tok * QKV_LD + 512 + head * 128 + quad * 8;
    bf16x8 b0 = *reinterpret_cast<const bf16x8*>(krow);
    bf16x8 b1 = *reinterpret_cast<const bf16x8*>(krow + 32);
    sacc[jt] = __builtin_amdgcn_mfma_f32_16x16x32_bf16(aq0, b0, sacc[jt], 0, 0, 0);
    sacc[jt] = __builtin_amdgcn_mfma_f32_16x16x32_bf16(aq1, b1, sacc[jt], 0, 0, 0);
  }

  #pragma unroll
  for (int jt = 0; jt < 3; ++jt) {
    int j = jt * 16 + l16;
    #pragma unroll
    for (int r = 0; r < 4; ++r) {
      int i = quad * 4 + r;
      bool valid = (j >= i) && (j <= i + 31) && (t0 - 32 + j >= 0);
      float tau = valid ? 1.f / (1.f + expf(-sacc[jt][r] * 0.125f)) : 0.f;
      Pl[i * 72 + j] = f2b(tau);
    }
  }
  #pragma unroll
  for (int r = 0; r < 4; ++r) Pl[(quad * 4 + r) * 72 + 48 + l16] = f2b(0.f);

  __syncthreads();   // uniform; orders LDS writes->reads across the block

  bf16x8 ap0 = *reinterpret_cast<const bf16x8*>((char*)Pl + l16 * 144 + quad * 16);
  bf16x8 ap1 = *reinterpret_cast<const bf16x8*>((char*)Pl + l16 * 144 + 64 + quad * 16);

  f32x4 macc[4] = {};
  #pragma unroll
  for (int nt = 0; nt < 4; ++nt) {
    int d = nt * 16 + l16;
    bf16x8 bv0 = *reinterpret_cast<const bf16x8*>(Vl + vt_addr(d, quad * 8));
    bf16x8 bv1 = *reinterpret_cast<const bf16x8*>(Vl + vt_addr(d, 32 + quad * 8));
    macc[nt] = __builtin_amdgcn_mfma_f32_16x16x32_bf16(ap0, bv0, macc[nt], 0, 0, 0);
    macc[nt] = __builtin_amdgcn_mfma_f32_16x16x32_bf16(ap1, bv1, macc[nt], 0, 0, 0);
  }

  #pragma unroll
  for (int nt = 0; nt < 4; ++nt)
    #pragma unroll
    for (int r = 0; r < 4; ++r)
      qkv[(size_t)(rowbase + quad * 4 + r) * QKV_LD + head * HD_DIM + nt * 16 + l16] =
          f2b(macc[nt][r]);
}

// ---------------------------------------------------------------------------
extern "C" void kernel_launch(void* const* d_in, const int* in_sizes, int n_in,
                              void* d_out, int out_size, void* d_ws, size_t ws_size,
                              hipStream_t stream)
{
  const void* x      = d_in[0];
  const void* pre_g  = d_in[1];
  const void* pre_b  = d_in[2];
  const void* wq     = d_in[3];
  const void* wkv    = d_in[4];
  const void* wo     = d_in[5];
  const void* attn_g = d_in[6];
  const void* attn_b = d_in[7];
  const void* freqs  = d_in[8];
  const void* phases = d_in[9];
  const void* amp    = d_in[10];
  const void* w_gate = d_in[11];
  const void* w_val  = d_in[12];
  const void* w_proj = d_in[13];
  const void* ffn_g  = d_in[14];
  const void* ffn_b  = d_in[15];
  const unsigned* xdet = (const unsigned*)x;

  char* ws = (char*)d_ws;
  bf16* Btqkv = (bf16*)(ws + 512);       // 1536 x 512
  bf16* Bto   = (bf16*)(ws + 1573376);   //  512 x 512
  bf16* Btg   = (bf16*)(ws + 2097664);   // 1536 x 512
  bf16* Btv   = (bf16*)(ws + 3670528);   // 1536 x 512
  bf16* Btp   = (bf16*)(ws + 5243392);   //  512 x 1536
  bf16* h     = (bf16*)(ws + 6816256);   // 8192 x 512   (h -> s1 -> y -> u)
  bf16* qkvb  = (bf16*)(ws + 15204864);  // 8192 x 1536  (q|kv; msg in-place; then act)
  bf16* gb    = qkvb;

  transpose_all_kernel<<<3328, 256, 0, stream>>>(
      wq, wkv, wo, w_gate, w_val, w_proj,
      Btqkv, Btqkv + 512 * 512, Bto, Btg, Btv, Btp, xdet);

  // h = LN(x)
  ln_kernel<<<2048, 256, 0, stream>>>(x, pre_g, pre_b, h, 0,
                                      nullptr, nullptr, nullptr, xdet, 1, 0);

  // qkv = h @ [wq|wkv]  (fused, N=1536): 128x128 tiles, 768 blocks
  gemm_tile_kernel<128><<<768, 256, 0, stream>>>(h, Btqkv, qkvb, nullptr,
                                                 1536, 512, 512, 0, 12);

  // msg = window-attention (in-place over q slot)
  attn_mfma_kernel<<<1024, 256, 0, stream>>>(qkvb);

  // s1 = h + msg @ wo  (N=512): 128x64 tiles, 512 blocks
  gemm_tile_kernel<64><<<512, 256, 0, stream>>>(qkvb, Bto, h, h,
                                                512, 512, QKV_LD, 1, 8);

  // y = LN(s1) * (1 + amp*sin(t*freqs+phases))
  ln_kernel<<<2048, 256, 0, stream>>>(h, attn_g, attn_b, h, 1,
                                      freqs, phases, amp, xdet, 0, 0);

  // act = silu(y @ w_gate) * (y @ w_val): 128x64 tiles, 1536 blocks
  gateval_kernel<<<1536, 256, 0, stream>>>(h, Btg, Btv, gb,
                                           1536, 512, 512, 24);

  // u = y + act @ w_proj  (N=512, K=1536): 128x64 tiles, 512 blocks
  gemm_tile_kernel<64><<<512, 256, 0, stream>>>(gb, Btp, h, h,
                                                512, 1536, QKV_LD, 1, 8);

  // out = LN(u)
  ln_kernel<<<2048, 256, 0, stream>>>(h, ffn_g, ffn_b, d_out, 0,
                                      nullptr, nullptr, nullptr, xdet, 0, 1);
}